// Round 6
// baseline (50.910 us; speedup 1.0000x reference)
//
#include <hip/hip_runtime.h>

// out[b] = clip( hardswish( dot(x[b,:], colsum(y)) ) + noise[b], -0.5, 0.5 )
// B = 8192, F = 4096, fp32. Memory-bound: compulsory 256 MB (x + y) -> ~42 us floor
// (harness ws-poison fill evicts L3 between replays, so inputs re-stream).
//
// Journal:
//  R1: 64-block colsum latency-bound (101 us @ 2.7% occupancy).
//  R2: 105 us; straggler = 16-block final reduce (256 un-unrolled strided loads).
//  R3: cooperative launch silently failed (output never written). Avoid.
//  R4: ticket+__threadfence fusion = 420 us (device fences serialize). Avoid.
//  R5: 4-dispatch tree (colsum 4x256 / reduce1 / reduce2 / wave-per-row rowdot)
//      = 50.7 us. ~83% of floor; slack = 2 tiny dispatches + gaps.
//  R6: 3 dispatches: halve partials (4x128 colsum), single-stage LDS-tree
//      reduce (256 blocks), rowdot unchanged.

namespace {

constexpr int F      = 4096;
constexpr int B      = 8192;
constexpr int NTHR   = 256;
constexpr int NSTRIP = 4;                 // 256 thr * float4 = 1024 cols per strip
constexpr int NSLAB  = 128;               // row slabs -> colsum grid 4 x 128
constexpr int RPS    = B / NSLAB;         // 64 rows per slab

__device__ __forceinline__ void f4_add(float4& a, const float4 b) {
    a.x += b.x; a.y += b.y; a.z += b.z; a.w += b.w;
}
__device__ __forceinline__ void f4_fma(float& a, const float4 xv, const float4 yv) {
    a = fmaf(xv.x, yv.x, a); a = fmaf(xv.y, yv.y, a);
    a = fmaf(xv.z, yv.z, a); a = fmaf(xv.w, yv.w, a);
}

// Stage 1: block (strip s, slab p) column-sums 64 rows of y into partial[p][...].
// 512 blocks (2/CU), fully coalesced float4 streaming. partial = 2 MB.
__global__ __launch_bounds__(NTHR) void colsum_k(
    const float* __restrict__ y, float* __restrict__ partial)
{
    const int s  = blockIdx.x;
    const int p  = blockIdx.y;
    const int c4 = s * NTHR + threadIdx.x;    // float4 column index
    const long row0 = (long)p * RPS;

    float4 acc = {0.f, 0.f, 0.f, 0.f};
#pragma unroll 8
    for (int r = 0; r < RPS; ++r)
        f4_add(acc, reinterpret_cast<const float4*>(y + (row0 + r) * F)[c4]);
    reinterpret_cast<float4*>(partial + (size_t)p * F)[c4] = acc;
}

// Stage 2: ysum[c] = sum_p partial[p][c], single dispatch.
// 256 blocks; block = 16 columns x 16 chunk-threads; each thread sums 8 slabs
// (unrolled), LDS tree folds the 16 chunks. Shallow chains, full-chip.
__global__ __launch_bounds__(NTHR) void reduce_k(
    const float* __restrict__ partial, float* __restrict__ ysum)
{
    const int t  = threadIdx.x;
    const int cl = t & 15;                    // column within block
    const int q  = t >> 4;                    // chunk 0..15
    const int c  = blockIdx.x * 16 + cl;

    float a = 0.f;
#pragma unroll
    for (int i = 0; i < NSLAB / 16; ++i)      // 8 slabs per chunk-thread
        a += partial[(size_t)(q * (NSLAB / 16) + i) * F + c];

    __shared__ float red[16][17];             // +1 pad (not strictly needed)
    red[q][cl] = a;
    __syncthreads();

    if (q == 0) {
        float s = 0.f;
#pragma unroll
        for (int k = 0; k < 16; ++k) s += red[k][cl];
        ysum[c] = s;
    }
}

// Stage 3: wave-per-row dot(x[b,:], ysum) -> hardswish -> +noise -> hardtanh.
// 2048 blocks x 4 waves = 8192 rows. No LDS, no __syncthreads.
__global__ __launch_bounds__(NTHR) void rowdot_k(
    const float* __restrict__ x, const float* __restrict__ ysum,
    const float* __restrict__ noise, float* __restrict__ out)
{
    const int wid  = threadIdx.x >> 6;
    const int lane = threadIdx.x & 63;
    const int b    = blockIdx.x * 4 + wid;

    const float4* xr = reinterpret_cast<const float4*>(x + (size_t)b * F);
    const float4* ys = reinterpret_cast<const float4*>(ysum);

    float a0 = 0.f, a1 = 0.f, a2 = 0.f, a3 = 0.f;
#pragma unroll
    for (int g = 0; g < 16; g += 4) {
        f4_fma(a0, xr[(g + 0) * 64 + lane], ys[(g + 0) * 64 + lane]);
        f4_fma(a1, xr[(g + 1) * 64 + lane], ys[(g + 1) * 64 + lane]);
        f4_fma(a2, xr[(g + 2) * 64 + lane], ys[(g + 2) * 64 + lane]);
        f4_fma(a3, xr[(g + 3) * 64 + lane], ys[(g + 3) * 64 + lane]);
    }
    float p = (a0 + a1) + (a2 + a3);
#pragma unroll
    for (int off = 32; off > 0; off >>= 1) p += __shfl_xor(p, off);

    if (lane == 0) {
        const float s = p;
        const float h = s * fminf(fmaxf(s + 3.0f, 0.0f), 6.0f) * (1.0f / 6.0f);
        const float r = h + noise[b];        // logsumexp over singleton == identity
        out[b] = fminf(fmaxf(r, -0.5f), 0.5f);
    }
}

} // namespace

extern "C" void kernel_launch(void* const* d_in, const int* in_sizes, int n_in,
                              void* d_out, int out_size, void* d_ws, size_t ws_size,
                              hipStream_t stream)
{
    const float* x     = (const float*)d_in[0];   // (B, F)
    const float* y     = (const float*)d_in[1];   // (B, F)
    const float* noise = (const float*)d_in[2];   // (B, 1)
    float*       out   = (float*)d_out;           // (B, 1) fp32

    // ws: partial[128][F] (2 MB) | ysum[F] (16 KB)
    float* partial = (float*)d_ws;
    float* ysum    = partial + (size_t)NSLAB * F;

    colsum_k<<<dim3(NSTRIP, NSLAB), NTHR, 0, stream>>>(y, partial);
    reduce_k<<<F / 16,              NTHR, 0, stream>>>(partial, ysum);
    rowdot_k<<<B / 4,               NTHR, 0, stream>>>(x, ysum, noise, out);
}